// Round 1
// baseline (335.181 us; speedup 1.0000x reference)
//
#include <hip/hip_runtime.h>

// Problem constants: B=2, S=4096, C=2048, HD=128, H=16
// GEMM: M=8192 (B*S), N=6144 (3*C: q,k,v), K=2048
// out = concat(q,k,v), each [B,S,H,HD] f32 = [8192, 2048] row-major.

#define M_DIM 8192
#define N_DIM 6144
#define K_DIM 2048
#define BM 128
#define BN 128
#define BK 64
#define EPS_RMS 1.1920929e-07f

typedef __bf16 bf16x8 __attribute__((ext_vector_type(8)));
typedef float f32x4 __attribute__((ext_vector_type(4)));

__device__ __forceinline__ void gload16(const void* g, void* l) {
  __builtin_amdgcn_global_load_lds(
      (const __attribute__((address_space(1))) unsigned int*)g,
      (__attribute__((address_space(3))) unsigned int*)l, 16, 0, 0);
}

__device__ __forceinline__ unsigned short f2bf(float f) {
  union { float f; unsigned u; } x; x.f = f;
  unsigned r = x.u + 0x7FFFu + ((x.u >> 16) & 1u);   // RNE
  return (unsigned short)(r >> 16);
}

__global__ void __launch_bounds__(256) cvt_kernel(const float* __restrict__ s,
                                                  unsigned short* __restrict__ d, int n4) {
  int i = blockIdx.x * blockDim.x + threadIdx.x;
  const int stride = gridDim.x * blockDim.x;
  for (; i < n4; i += stride) {
    const float4 v = reinterpret_cast<const float4*>(s)[i];
    ushort4 o;
    o.x = f2bf(v.x); o.y = f2bf(v.y); o.z = f2bf(v.z); o.w = f2bf(v.w);
    reinterpret_cast<ushort4*>(d)[i] = o;
  }
}

// Fused GEMM (+bias, per-head RMSNorm, RoPE on q/k sections).
// xbf: [8192][2048] bf16, wbf: [6144][2048] bf16 (rows = output cols, torch Linear W layout)
__global__ void __launch_bounds__(256) gemm_fused(
    const unsigned short* __restrict__ xbf, const unsigned short* __restrict__ wbf,
    const float* __restrict__ rope,
    const float* __restrict__ bq, const float* __restrict__ bk, const float* __restrict__ bv,
    const float* __restrict__ qnw, const float* __restrict__ knw,
    float* __restrict__ dout) {
  // XCD-bijective swizzle: 3072 blocks, 3072 % 8 == 0
  const int id = blockIdx.x;
  const int sw = (id & 7) * (3072 / 8) + (id >> 3);
  const int bm = sw / (N_DIM / BN);   // 0..63
  const int bn = sw % (N_DIM / BN);   // 0..47
  const int m0 = bm * BM;
  const int n0 = bn * BN;

  const int tid = threadIdx.x;
  const int w = tid >> 6;       // wave 0..3
  const int l = tid & 63;
  const int l15 = l & 15;
  const int lhi = l >> 4;       // 0..3
  const int srcSlot = (l & 7) ^ (l >> 3);  // inverse swizzle for staging source

  __shared__ __align__(16) unsigned short As[BM * BK];  // 16 KB, swizzled layout
  __shared__ __align__(16) unsigned short Bs[BN * BK];  // 16 KB

  f32x4 acc[2][8];
#pragma unroll
  for (int a = 0; a < 2; ++a)
#pragma unroll
    for (int b = 0; b < 8; ++b) acc[a][b] = (f32x4){0.f, 0.f, 0.f, 0.f};

  // staging pointers: chunk c = 4*i + w covers rows 8c..8c+7 of the tile.
  // lane l -> row 8c + (l>>3), 16B slot (l&7)^(l>>3)  (so LDS slot s holds col-chunk s^(row&7))
  const unsigned short* aPtr = xbf + (((size_t)(m0 + 8 * w + (l >> 3))) << 11) + srcSlot * 8;
  const unsigned short* bPtr = wbf + (((size_t)(n0 + 8 * w + (l >> 3))) << 11) + srcSlot * 8;
  char* aLds = (char*)As + w * 1024;
  char* bLds = (char*)Bs + w * 1024;

  const int aRow0 = (w * 32 + l15) * 128;        // byte offset of A row (wr=0)
  const int aRow1 = (w * 32 + 16 + l15) * 128;   // wr=1
  const int xorv = (l & 7);

  for (int kt = 0; kt < K_DIM / BK; ++kt) {
#pragma unroll
    for (int i = 0; i < 4; ++i) {
      gload16(aPtr + (size_t)i * (32 * 2048), aLds + i * 4096);
      gload16(bPtr + (size_t)i * (32 * 2048), bLds + i * 4096);
    }
    __syncthreads();
#pragma unroll
    for (int kk = 0; kk < 2; ++kk) {
      const int slotX = ((kk * 4 + lhi) ^ xorv) * 16;
      bf16x8 a0 = *(const bf16x8*)((const char*)As + aRow0 + slotX);
      bf16x8 a1 = *(const bf16x8*)((const char*)As + aRow1 + slotX);
#pragma unroll
      for (int f = 0; f < 8; ++f) {
        bf16x8 bb = *(const bf16x8*)((const char*)Bs + (f * 16 + l15) * 128 + slotX);
        acc[0][f] = __builtin_amdgcn_mfma_f32_16x16x32_bf16(a0, bb, acc[0][f], 0, 0, 0);
        acc[1][f] = __builtin_amdgcn_mfma_f32_16x16x32_bf16(a1, bb, acc[1][f], 0, 0, 0);
      }
    }
    aPtr += BK;
    bPtr += BK;
    __syncthreads();
  }

  // ---- fused epilogue ----
  // section: 0=q,1=k,2=v; tile spans exactly one head (BN==HD==128)
  const int sec = bn >> 4;
  const int colBase = (bn & 15) << 7;  // col within section, multiple of 128
  const float* bias = sec == 0 ? bq : (sec == 1 ? bk : bv);
  float* outSec = dout + ((size_t)sec << 24);  // 8192*2048 = 2^24

  float biasv[8];
#pragma unroll
  for (int f = 0; f < 8; ++f) biasv[f] = bias[colBase + f * 16 + l15];

  if (sec < 2) {
    const float* nwp = sec ? knw : qnw;
    float nwv[8];
#pragma unroll
    for (int f = 0; f < 8; ++f) nwv[f] = nwp[f * 16 + l15];
#pragma unroll
    for (int wr = 0; wr < 2; ++wr) {
#pragma unroll
      for (int r = 0; r < 4; ++r) {
        const int m = m0 + w * 32 + wr * 16 + lhi * 4 + r;
        float t[8];
        float ss = 0.f;
#pragma unroll
        for (int f = 0; f < 8; ++f) {
          const float v0 = acc[wr][f][r] + biasv[f];
          t[f] = v0;
          ss += v0 * v0;
        }
        ss += __shfl_xor(ss, 1);
        ss += __shfl_xor(ss, 2);
        ss += __shfl_xor(ss, 4);
        ss += __shfl_xor(ss, 8);
        const float inv = rsqrtf(ss * (1.0f / 128.0f) + EPS_RMS);
        const float* rp = rope + (((size_t)(m & 4095)) << 8);  // [s][64][2][2]
        float* orow = outSec + (size_t)m * 2048 + colBase + l15;
#pragma unroll
        for (int f = 0; f < 8; ++f) {
          const float tn = t[f] * inv * nwv[f];
          const float pn = __shfl_xor(tn, 1);  // partner col^1
          const int j = (f * 16 + l15) >> 1;
          // even col: cos*t + (-sin)*partner ; odd col: cos*t + sin*partner
          const float o = fmaf(rp[4 * j], tn, rp[4 * j + 1 + (l & 1)] * pn);
          orow[f * 16] = o;
        }
      }
    }
  } else {
#pragma unroll
    for (int wr = 0; wr < 2; ++wr) {
#pragma unroll
      for (int r = 0; r < 4; ++r) {
        const int m = m0 + w * 32 + wr * 16 + lhi * 4 + r;
        float* orow = outSec + (size_t)m * 2048 + colBase + l15;
#pragma unroll
        for (int f = 0; f < 8; ++f) orow[f * 16] = acc[wr][f][r] + biasv[f];
      }
    }
  }
}

extern "C" void kernel_launch(void* const* d_in, const int* in_sizes, int n_in,
                              void* d_out, int out_size, void* d_ws, size_t ws_size,
                              hipStream_t stream) {
  const float* x = (const float*)d_in[0];
  const float* rope = (const float*)d_in[1];
  const float* wq = (const float*)d_in[2];
  const float* bq = (const float*)d_in[3];
  const float* wk = (const float*)d_in[4];
  const float* bk = (const float*)d_in[5];
  const float* wv = (const float*)d_in[6];
  const float* bv = (const float*)d_in[7];
  const float* qnw = (const float*)d_in[8];
  const float* knw = (const float*)d_in[9];

  unsigned short* xbf = (unsigned short*)d_ws;                 // 8192*2048 bf16 = 32 MB
  unsigned short* wbf = xbf + (size_t)M_DIM * K_DIM;           // 6144*2048 bf16 = 24 MB

  cvt_kernel<<<2048, 256, 0, stream>>>(x, xbf, M_DIM * K_DIM / 4);
  cvt_kernel<<<1024, 256, 0, stream>>>(wq, wbf, K_DIM * K_DIM / 4);
  cvt_kernel<<<1024, 256, 0, stream>>>(wk, wbf + (size_t)K_DIM * K_DIM, K_DIM * K_DIM / 4);
  cvt_kernel<<<1024, 256, 0, stream>>>(wv, wbf + (size_t)2 * K_DIM * K_DIM, K_DIM * K_DIM / 4);

  gemm_fused<<<(M_DIM / BM) * (N_DIM / BN), 256, 0, stream>>>(
      xbf, wbf, rope, bq, bk, bv, qnw, knw, (float*)d_out);
}

// Round 2
// 287.111 us; speedup vs baseline: 1.1674x; 1.1674x over previous
//
#include <hip/hip_runtime.h>

// B=2, S=4096, C=2048, HD=128, H=16
// GEMM: M=8192 (B*S), N=6144 (3*C), K=2048; out = concat(q,k,v) f32 [8192,2048] each.

#define M_DIM 8192
#define N_DIM 6144
#define K_DIM 2048
#define NKT 32            // K tiles of 64
#define EPS_RMS 1.1920929e-07f

typedef __bf16 bf16x8 __attribute__((ext_vector_type(8)));
typedef float f32x4 __attribute__((ext_vector_type(4)));

__device__ __forceinline__ void gload16(const void* g, void* l) {
  __builtin_amdgcn_global_load_lds(
      (const __attribute__((address_space(1))) unsigned int*)g,
      (__attribute__((address_space(3))) unsigned int*)l, 16, 0, 0);
}

__device__ __forceinline__ unsigned ldsoff(const void* p) {
  return (unsigned)(unsigned long long)(const __attribute__((address_space(3))) char*)p;
}

__device__ __forceinline__ unsigned short f2bf(float f) {
  union { float f; unsigned u; } x; x.f = f;
  unsigned r = x.u + 0x7FFFu + ((x.u >> 16) & 1u);   // RNE
  return (unsigned short)(r >> 16);
}

__global__ void __launch_bounds__(256) cvt_kernel(const float* __restrict__ s,
                                                  unsigned short* __restrict__ d, int n4) {
  int i = blockIdx.x * blockDim.x + threadIdx.x;
  const int stride = gridDim.x * blockDim.x;
  for (; i < n4; i += stride) {
    const float4 v = reinterpret_cast<const float4*>(s)[i];
    ushort4 o;
    o.x = f2bf(v.x); o.y = f2bf(v.y); o.z = f2bf(v.z); o.w = f2bf(v.w);
    reinterpret_cast<ushort4*>(d)[i] = o;
  }
}

#define DSR(dst, base, IMM) \
  asm volatile("ds_read_b128 %0, %1 offset:" IMM : "=v"(dst) : "v"(base))

#define MFMA_PH(MH, NH)                                                              \
  {                                                                                  \
    _Pragma("unroll")                                                                \
    for (int mf4 = 0; mf4 < 4; ++mf4) {                                              \
      _Pragma("unroll")                                                              \
      for (int nf2 = 0; nf2 < 2; ++nf2) {                                            \
        f32x4& c = acc[(MH) * 4 + mf4][(NH) * 2 + nf2];                              \
        c = __builtin_amdgcn_mfma_f32_16x16x32_bf16(                                 \
            __builtin_bit_cast(bf16x8, Af[mf4][0]),                                  \
            __builtin_bit_cast(bf16x8, Bf[nf2][0]), c, 0, 0, 0);                     \
        c = __builtin_amdgcn_mfma_f32_16x16x32_bf16(                                 \
            __builtin_bit_cast(bf16x8, Af[mf4][1]),                                  \
            __builtin_bit_cast(bf16x8, Bf[nf2][1]), c, 0, 0, 0);                     \
      }                                                                              \
    }                                                                                \
  }

// 256x256 tile, BK=64, 8 waves (2M x 4N), per-wave 128x64.
// LDS: A[2 buf][4 quarters][64 rows][64 cols] bf16 = 64 KB; B same = 64 KB.
__global__ void __launch_bounds__(512, 2) gemm_fused(
    const unsigned short* __restrict__ xbf, const unsigned short* __restrict__ wbf,
    const float* __restrict__ rope,
    const float* __restrict__ bq, const float* __restrict__ bk, const float* __restrict__ bv,
    const float* __restrict__ qnw, const float* __restrict__ knw,
    float* __restrict__ dout) {
  const int id = blockIdx.x;
  const int sw = (id & 7) * 96 + (id >> 3);    // 768 % 8 == 0, bijective
  const int bm = sw / 24;
  const int bn = sw - bm * 24;
  const int m0 = bm << 8, n0 = bn << 8;
  const int tid = threadIdx.x;
  const int w = tid >> 6, l = tid & 63;
  const int l15 = l & 15, lhi = l >> 4;
  const int wr = w >> 2, wc = w & 3;

  __shared__ __align__(16) unsigned short As[32768];   // 64 KB
  __shared__ __align__(16) unsigned short Bs[32768];   // 64 KB

  // ---- staging (linear LDS dest, inverse-swizzled global source) ----
  const int srow = tid >> 3;                       // 0..63 within a quarter
  const int schunk = (tid & 7) ^ (srow & 7);       // involution
  const unsigned short* aSrc = xbf + ((size_t)(m0 + srow) << 11) + (schunk << 3);
  const unsigned short* bSrc = wbf + ((size_t)(n0 + srow) << 11) + (schunk << 3);
  char* aDst = (char*)As + (w << 10);
  char* bDst = (char*)Bs + (w << 10);

#define STA(KT, Q) gload16(aSrc + ((Q) << 17) + ((KT) << 6), aDst + ((((KT) & 1) << 15) + ((Q) << 13)))
#define STB(KT, Q) gload16(bSrc + ((Q) << 17) + ((KT) << 6), bDst + ((((KT) & 1) << 15) + ((Q) << 13)))

  // ---- ds_read bases (swizzled read side) ----
  const int sl0 = ((lhi ^ (l15 & 7)) << 4);
  const int sl1 = (((lhi + 4) ^ (l15 & 7)) << 4);
  unsigned a0 = ldsoff(As) + (wr << 14) + (l15 << 7) + sl0;
  unsigned a1 = ldsoff(As) + (wr << 14) + (l15 << 7) + sl1;
  unsigned b0 = ldsoff(Bs) + (wc << 13) + (l15 << 7) + sl0;
  unsigned b1 = ldsoff(Bs) + (wc << 13) + (l15 << 7) + sl1;

  f32x4 acc[8][4];
#pragma unroll
  for (int i = 0; i < 8; ++i)
#pragma unroll
    for (int j = 0; j < 4; ++j) acc[i][j] = (f32x4){0.f, 0.f, 0.f, 0.f};

  f32x4 Af[4][2], Bf[2][2];

  // ---- prologue: kt0 full (8), then kt1 in steady-state pattern (2 + 6) ----
  STA(0, 0); STA(0, 1); STA(0, 2); STA(0, 3);
  STB(0, 0); STB(0, 1); STB(0, 2); STB(0, 3);
  STA(1, 0); STA(1, 2);
  STA(1, 1); STA(1, 3); STB(1, 0); STB(1, 1); STB(1, 2); STB(1, 3);
  asm volatile("s_waitcnt vmcnt(8)");       // kt0 landed; kt1's 8 in flight
  __builtin_amdgcn_s_barrier();

  for (int kt = 0; kt < NKT; ++kt) {
    // ---- phase 0: (mh0, nh0) — A q0/q2 + B nh0; stage 6-set for kt+1 ----
    DSR(Af[0][0], a0, "0");    DSR(Af[1][0], a0, "2048");
    DSR(Af[2][0], a0, "4096"); DSR(Af[3][0], a0, "6144");
    DSR(Af[0][1], a1, "0");    DSR(Af[1][1], a1, "2048");
    DSR(Af[2][1], a1, "4096"); DSR(Af[3][1], a1, "6144");
    DSR(Bf[0][0], b0, "0");    DSR(Bf[1][0], b0, "2048");
    DSR(Bf[0][1], b1, "0");    DSR(Bf[1][1], b1, "2048");
    if (kt >= 1 && kt <= NKT - 2) {
      STA(kt + 1, 1); STA(kt + 1, 3);
      STB(kt + 1, 0); STB(kt + 1, 1); STB(kt + 1, 2); STB(kt + 1, 3);
    }
    __builtin_amdgcn_s_barrier();
    asm volatile("s_waitcnt lgkmcnt(0)");
    __builtin_amdgcn_sched_barrier(0);
    __builtin_amdgcn_s_setprio(1);
    MFMA_PH(0, 0);
    __builtin_amdgcn_s_setprio(0);
    __builtin_amdgcn_s_barrier();
    // ---- phase 1: (mh0, nh1) — B nh1 only ----
    DSR(Bf[0][0], b0, "4096"); DSR(Bf[1][0], b0, "6144");
    DSR(Bf[0][1], b1, "4096"); DSR(Bf[1][1], b1, "6144");
    __builtin_amdgcn_s_barrier();
    asm volatile("s_waitcnt lgkmcnt(0)");
    __builtin_amdgcn_sched_barrier(0);
    __builtin_amdgcn_s_setprio(1);
    MFMA_PH(0, 1);
    __builtin_amdgcn_s_setprio(0);
    __builtin_amdgcn_s_barrier();
    // ---- phase 2: (mh1, nh1) — A q1/q3 ----
    DSR(Af[0][0], a0, "8192");  DSR(Af[1][0], a0, "10240");
    DSR(Af[2][0], a0, "12288"); DSR(Af[3][0], a0, "14336");
    DSR(Af[0][1], a1, "8192");  DSR(Af[1][1], a1, "10240");
    DSR(Af[2][1], a1, "12288"); DSR(Af[3][1], a1, "14336");
    __builtin_amdgcn_s_barrier();
    asm volatile("s_waitcnt lgkmcnt(0)");
    __builtin_amdgcn_sched_barrier(0);
    __builtin_amdgcn_s_setprio(1);
    MFMA_PH(1, 1);
    __builtin_amdgcn_s_setprio(0);
    __builtin_amdgcn_s_barrier();
    // ---- phase 3: (mh1, nh0) — B nh0 again; stage A q0/q2 of kt+2 ----
    DSR(Bf[0][0], b0, "0"); DSR(Bf[1][0], b0, "2048");
    DSR(Bf[0][1], b1, "0"); DSR(Bf[1][1], b1, "2048");
    if (kt <= NKT - 3) { STA(kt + 2, 0); STA(kt + 2, 2); }
    __builtin_amdgcn_s_barrier();
    asm volatile("s_waitcnt lgkmcnt(0)");
    __builtin_amdgcn_sched_barrier(0);
    __builtin_amdgcn_s_setprio(1);
    MFMA_PH(1, 0);
    __builtin_amdgcn_s_setprio(0);
    // ---- K-tile boundary: counted vmcnt (kt+2's 2 A-loads stay in flight) ----
    if (kt < NKT - 2)       { asm volatile("s_waitcnt vmcnt(2)"); }
    else if (kt == NKT - 2) { asm volatile("s_waitcnt vmcnt(0)"); }
    __builtin_amdgcn_s_barrier();
    a0 ^= 32768u; a1 ^= 32768u; b0 ^= 32768u; b1 ^= 32768u;
  }

  // ---- fused epilogue: bias (+ per-head RMSNorm + RoPE for q,k) ----
  __syncthreads();
  float* scr = (float*)As;                       // [8 waves][128 rows] partials
  const int sec = bn >> 3;                       // 0=q 1=k 2=v
  const int nsec = (n0 & 2047) + (wc << 6);      // col-in-section base (+nf*16+l15)
  const float* bias = sec == 0 ? bq : (sec == 1 ? bk : bv);
  float biasv[4];
#pragma unroll
  for (int nf = 0; nf < 4; ++nf) biasv[nf] = bias[nsec + nf * 16 + l15];
  const size_t outBase = ((size_t)sec << 24);

  if (sec < 2) {
    const float* nwp = sec ? knw : qnw;
    const int colh = (wc & 1) << 6;              // col-in-head base for this wave
    float nwv[4];
#pragma unroll
    for (int nf = 0; nf < 4; ++nf) nwv[nf] = nwp[colh + nf * 16 + l15];
    float ssv[8][4];
#pragma unroll
    for (int mf = 0; mf < 8; ++mf) {
#pragma unroll
      for (int j = 0; j < 4; ++j) {
        float ss = 0.f;
#pragma unroll
        for (int nf = 0; nf < 4; ++nf) {
          const float t = acc[mf][nf][j] + biasv[nf];
          ss += t * t;
        }
        ss += __shfl_xor(ss, 1);
        ss += __shfl_xor(ss, 2);
        ss += __shfl_xor(ss, 4);
        ss += __shfl_xor(ss, 8);
        ssv[mf][j] = ss;                          // sum over this wave's 64 cols
      }
    }
    if (l15 == 0) {
#pragma unroll
      for (int mf = 0; mf < 8; ++mf)
#pragma unroll
        for (int j = 0; j < 4; ++j)
          scr[(w << 7) + mf * 16 + (lhi << 2) + j] = ssv[mf][j];
    }
    __syncthreads();
#pragma unroll
    for (int mf = 0; mf < 8; ++mf) {
#pragma unroll
      for (int j = 0; j < 4; ++j) {
        const float tot = ssv[mf][j] + scr[((w ^ 1) << 7) + mf * 16 + (lhi << 2) + j];
        const float inv = rsqrtf(tot * (1.0f / 128.0f) + EPS_RMS);
        const int m = m0 + (wr << 7) + mf * 16 + (lhi << 2) + j;
        const float* rp = rope + ((size_t)(m & 4095) << 8);
        float* orow = dout + outBase + ((size_t)m << 11) + nsec + l15;
#pragma unroll
        for (int nf = 0; nf < 4; ++nf) {
          const float tn = (acc[mf][nf][j] + biasv[nf]) * inv * nwv[nf];
          const float pn = __shfl_xor(tn, 1);     // partner col^1
          const int ch = colh + nf * 16 + l15;    // col in head
          const int jr = ch >> 1;
          const float o = fmaf(rp[jr << 2], tn, rp[(jr << 2) + 1 + (ch & 1)] * pn);
          orow[nf << 4] = o;
        }
      }
    }
  } else {
#pragma unroll
    for (int mf = 0; mf < 8; ++mf)
#pragma unroll
      for (int j = 0; j < 4; ++j) {
        const int m = m0 + (wr << 7) + mf * 16 + (lhi << 2) + j;
        float* orow = dout + outBase + ((size_t)m << 11) + nsec + l15;
#pragma unroll
        for (int nf = 0; nf < 4; ++nf) orow[nf << 4] = acc[mf][nf][j] + biasv[nf];
      }
  }
}

extern "C" void kernel_launch(void* const* d_in, const int* in_sizes, int n_in,
                              void* d_out, int out_size, void* d_ws, size_t ws_size,
                              hipStream_t stream) {
  const float* x = (const float*)d_in[0];
  const float* rope = (const float*)d_in[1];
  const float* wq = (const float*)d_in[2];
  const float* bq = (const float*)d_in[3];
  const float* wk = (const float*)d_in[4];
  const float* bk = (const float*)d_in[5];
  const float* wv = (const float*)d_in[6];
  const float* bv = (const float*)d_in[7];
  const float* qnw = (const float*)d_in[8];
  const float* knw = (const float*)d_in[9];

  unsigned short* xbf = (unsigned short*)d_ws;                 // 32 MB
  unsigned short* wbf = xbf + (size_t)M_DIM * K_DIM;           // 24 MB

  cvt_kernel<<<2048, 256, 0, stream>>>(x, xbf, M_DIM * K_DIM / 4);
  cvt_kernel<<<1024, 256, 0, stream>>>(wq, wbf, K_DIM * K_DIM / 4);
  cvt_kernel<<<1024, 256, 0, stream>>>(wk, wbf + (size_t)K_DIM * K_DIM, K_DIM * K_DIM / 4);
  cvt_kernel<<<1024, 256, 0, stream>>>(wv, wbf + (size_t)2 * K_DIM * K_DIM, K_DIM * K_DIM / 4);

  gemm_fused<<<(M_DIM / 256) * (N_DIM / 256), 512, 0, stream>>>(
      xbf, wbf, rope, bq, bk, bv, qnw, knw, (float*)d_out);
}

// Round 3
// 265.234 us; speedup vs baseline: 1.2637x; 1.0825x over previous
//
#include <hip/hip_runtime.h>

// B=2, S=4096, C=2048, HD=128, H=16
// GEMM: M=8192 (B*S), N=6144 (3*C), K=2048; out = concat(q,k,v) f32 [8192,2048] each.

#define M_DIM 8192
#define N_DIM 6144
#define K_DIM 2048
#define NKT 32            // K tiles of 64
#define EPS_RMS 1.1920929e-07f

typedef __bf16 bf16x8 __attribute__((ext_vector_type(8)));
typedef float f32x4 __attribute__((ext_vector_type(4)));

__device__ __forceinline__ void gload16(const void* g, void* l) {
  __builtin_amdgcn_global_load_lds(
      (const __attribute__((address_space(1))) unsigned int*)g,
      (__attribute__((address_space(3))) unsigned int*)l, 16, 0, 0);
}

__device__ __forceinline__ unsigned ldsoff(const void* p) {
  return (unsigned)(unsigned long long)(const __attribute__((address_space(3))) char*)p;
}

__device__ __forceinline__ unsigned short f2bf(float f) {
  union { float f; unsigned u; } x; x.f = f;
  unsigned r = x.u + 0x7FFFu + ((x.u >> 16) & 1u);   // RNE
  return (unsigned short)(r >> 16);
}

__global__ void __launch_bounds__(256) cvt_kernel(const float* __restrict__ s,
                                                  unsigned short* __restrict__ d, int n4) {
  int i = blockIdx.x * blockDim.x + threadIdx.x;
  const int stride = gridDim.x * blockDim.x;
  for (; i < n4; i += stride) {
    const float4 v = reinterpret_cast<const float4*>(s)[i];
    ushort4 o;
    o.x = f2bf(v.x); o.y = f2bf(v.y); o.z = f2bf(v.z); o.w = f2bf(v.w);
    reinterpret_cast<ushort4*>(d)[i] = o;
  }
}

#define DSR(dst, base, IMM) \
  asm volatile("ds_read_b128 %0, %1 offset:" IMM : "=v"(dst) : "v"(base))

#define MFMA_PH(MH, NH)                                                              \
  {                                                                                  \
    _Pragma("unroll")                                                                \
    for (int mf4 = 0; mf4 < 4; ++mf4) {                                              \
      _Pragma("unroll")                                                              \
      for (int nf2 = 0; nf2 < 2; ++nf2) {                                            \
        f32x4& c = acc[(MH) * 4 + mf4][(NH) * 2 + nf2];                              \
        c = __builtin_amdgcn_mfma_f32_16x16x32_bf16(                                 \
            __builtin_bit_cast(bf16x8, Af[mf4][0]),                                  \
            __builtin_bit_cast(bf16x8, Bf[NH][nf2][0]), c, 0, 0, 0);                 \
        c = __builtin_amdgcn_mfma_f32_16x16x32_bf16(                                 \
            __builtin_bit_cast(bf16x8, Af[mf4][1]),                                  \
            __builtin_bit_cast(bf16x8, Bf[NH][nf2][1]), c, 0, 0, 0);                 \
      }                                                                              \
    }                                                                                \
  }

// 256x256 tile, BK=64, 8 waves (2M x 4N), per-wave 128x64.
// LDS: A[2 buf][4 quarters][64 rows][64 cols] bf16 = 64 KB; B same = 64 KB.
// 3 phases/K-tile: ph0 {A-half0(8r)+B-nh0(4r), 16 MFMA}, ph1 {B-nh1(4r), 16 MFMA},
// ph2 {A-half1(8r), 32 MFMA}. B halves held in regs across the tile (24 reads total).
// Staging: only kt+1 (parity dbuf), 4/2/2 per phase; waits vmcnt(6) / vmcnt(2),
// each immediately before a barrier (cross-wave LDS visibility).
__global__ void __launch_bounds__(512, 2) gemm_fused(
    const unsigned short* __restrict__ xbf, const unsigned short* __restrict__ wbf,
    const float* __restrict__ rope,
    const float* __restrict__ bq, const float* __restrict__ bk, const float* __restrict__ bv,
    const float* __restrict__ qnw, const float* __restrict__ knw,
    float* __restrict__ dout) {
  const int id = blockIdx.x;
  const int sw = (id & 7) * 96 + (id >> 3);    // 768 % 8 == 0, bijective
  const int bm = sw / 24;
  const int bn = sw - bm * 24;
  const int m0 = bm << 8, n0 = bn << 8;
  const int tid = threadIdx.x;
  const int w = tid >> 6, l = tid & 63;
  const int l15 = l & 15, lhi = l >> 4;
  const int wr = w >> 2, wc = w & 3;

  __shared__ __align__(16) unsigned short As[32768];   // 64 KB
  __shared__ __align__(16) unsigned short Bs[32768];   // 64 KB

  // ---- staging (linear LDS dest, inverse-swizzled global source) ----
  const int srow = tid >> 3;                       // 0..63 within a quarter
  const int schunk = (tid & 7) ^ (srow & 7);       // involution
  const unsigned short* aSrc = xbf + ((size_t)(m0 + srow) << 11) + (schunk << 3);
  const unsigned short* bSrc = wbf + ((size_t)(n0 + srow) << 11) + (schunk << 3);
  char* aDst = (char*)As + (w << 10);
  char* bDst = (char*)Bs + (w << 10);

#define STA(KT, Q) gload16(aSrc + ((size_t)(Q) << 17) + ((KT) << 6), aDst + ((((KT) & 1) << 15) + ((Q) << 13)))
#define STB(KT, Q) gload16(bSrc + ((size_t)(Q) << 17) + ((KT) << 6), bDst + ((((KT) & 1) << 15) + ((Q) << 13)))

  // ---- ds_read bases (swizzled read side) ----
  const int sl0 = ((lhi ^ (l15 & 7)) << 4);
  const int sl1 = (((lhi + 4) ^ (l15 & 7)) << 4);
  unsigned a0 = ldsoff(As) + (wr << 14) + (l15 << 7) + sl0;
  unsigned a1 = ldsoff(As) + (wr << 14) + (l15 << 7) + sl1;
  unsigned b0 = ldsoff(Bs) + (wc << 13) + (l15 << 7) + sl0;
  unsigned b1 = ldsoff(Bs) + (wc << 13) + (l15 << 7) + sl1;

  f32x4 acc[8][4];
#pragma unroll
  for (int i = 0; i < 8; ++i)
#pragma unroll
    for (int j = 0; j < 4; ++j) acc[i][j] = (f32x4){0.f, 0.f, 0.f, 0.f};

  f32x4 Af[4][2];        // current A-half fragments
  f32x4 Bf[2][2][2];     // both B halves held across the K-tile

  // ---- prologue: kt0's 6 ph0-needed loads, then its 2 A q1/q3 ----
  STA(0, 0); STA(0, 2);
  STB(0, 0); STB(0, 1); STB(0, 2); STB(0, 3);
  STA(0, 1); STA(0, 3);
  asm volatile("s_waitcnt vmcnt(2)");       // ph0 set landed; A q1/q3 in flight
  __builtin_amdgcn_s_barrier();

  for (int kt = 0; kt < NKT; ++kt) {
    const bool notLast = (kt < NKT - 1);
    // ---- phase 0: (mh0, nh0) — A half0 (8r) + B nh0 (4r); stage 4 ----
    DSR(Af[0][0], a0, "0");    DSR(Af[1][0], a0, "2048");
    DSR(Af[2][0], a0, "4096"); DSR(Af[3][0], a0, "6144");
    DSR(Af[0][1], a1, "0");    DSR(Af[1][1], a1, "2048");
    DSR(Af[2][1], a1, "4096"); DSR(Af[3][1], a1, "6144");
    DSR(Bf[0][0][0], b0, "0");    DSR(Bf[0][1][0], b0, "2048");
    DSR(Bf[0][0][1], b1, "0");    DSR(Bf[0][1][1], b1, "2048");
    if (notLast) { STA(kt + 1, 0); STA(kt + 1, 2); STB(kt + 1, 0); STB(kt + 1, 1); }
    __builtin_amdgcn_s_barrier();
    asm volatile("s_waitcnt lgkmcnt(0)");
    __builtin_amdgcn_sched_barrier(0);
    __builtin_amdgcn_s_setprio(1);
    MFMA_PH(0, 0);
    __builtin_amdgcn_s_setprio(0);
    __builtin_amdgcn_s_barrier();
    // ---- phase 1: (mh0, nh1) — B nh1 (4r); stage 2 ----
    DSR(Bf[1][0][0], b0, "4096"); DSR(Bf[1][1][0], b0, "6144");
    DSR(Bf[1][0][1], b1, "4096"); DSR(Bf[1][1][1], b1, "6144");
    if (notLast) { STB(kt + 1, 2); STB(kt + 1, 3); }
    __builtin_amdgcn_s_barrier();
    asm volatile("s_waitcnt lgkmcnt(0)");
    __builtin_amdgcn_sched_barrier(0);
    __builtin_amdgcn_s_setprio(1);
    MFMA_PH(0, 1);
    __builtin_amdgcn_s_setprio(0);
    // W1: this-kt A q1/q3 (staged at kt-1 ph2) must be LDS-visible before ph2 reads.
    if (notLast) { asm volatile("s_waitcnt vmcnt(6)"); }
    else         { asm volatile("s_waitcnt vmcnt(0)"); }
    __builtin_amdgcn_s_barrier();
    // ---- phase 2: (mh1) — A half1 (8r); 32 MFMA (nh1 then nh0, B in regs); stage 2 ----
    DSR(Af[0][0], a0, "8192");  DSR(Af[1][0], a0, "10240");
    DSR(Af[2][0], a0, "12288"); DSR(Af[3][0], a0, "14336");
    DSR(Af[0][1], a1, "8192");  DSR(Af[1][1], a1, "10240");
    DSR(Af[2][1], a1, "12288"); DSR(Af[3][1], a1, "14336");
    if (notLast) { STA(kt + 1, 1); STA(kt + 1, 3); }
    __builtin_amdgcn_s_barrier();
    asm volatile("s_waitcnt lgkmcnt(0)");
    __builtin_amdgcn_sched_barrier(0);
    __builtin_amdgcn_s_setprio(1);
    MFMA_PH(1, 1);
    MFMA_PH(1, 0);
    __builtin_amdgcn_s_setprio(0);
    // W2: kt+1's ph0 set (6 oldest) must be visible; leave its A q1/q3 in flight.
    if (notLast) { asm volatile("s_waitcnt vmcnt(2)"); }
    __builtin_amdgcn_s_barrier();
    a0 ^= 32768u; a1 ^= 32768u; b0 ^= 32768u; b1 ^= 32768u;
  }

  // ---- fused epilogue: bias (+ per-head RMSNorm + RoPE for q,k) ----
  float* scr = (float*)As;                       // [8 waves][128 rows] partials
  const int sec = bn >> 3;                       // 0=q 1=k 2=v
  const int nsec = (n0 & 2047) + (wc << 6);      // col-in-section base (+nf*16+l15)
  const float* bias = sec == 0 ? bq : (sec == 1 ? bk : bv);
  float biasv[4];
#pragma unroll
  for (int nf = 0; nf < 4; ++nf) biasv[nf] = bias[nsec + nf * 16 + l15];
  const size_t outBase = ((size_t)sec << 24);

  if (sec < 2) {
    const float* nwp = sec ? knw : qnw;
    const int colh = (wc & 1) << 6;              // col-in-head base for this wave
    float nwv[4];
#pragma unroll
    for (int nf = 0; nf < 4; ++nf) nwv[nf] = nwp[colh + nf * 16 + l15];
    float ssv[8][4];
#pragma unroll
    for (int mf = 0; mf < 8; ++mf) {
#pragma unroll
      for (int j = 0; j < 4; ++j) {
        float ss = 0.f;
#pragma unroll
        for (int nf = 0; nf < 4; ++nf) {
          const float t = acc[mf][nf][j] + biasv[nf];
          ss += t * t;
        }
        ss += __shfl_xor(ss, 1);
        ss += __shfl_xor(ss, 2);
        ss += __shfl_xor(ss, 4);
        ss += __shfl_xor(ss, 8);
        ssv[mf][j] = ss;                          // sum over this wave's 64 cols
      }
    }
    if (l15 == 0) {
#pragma unroll
      for (int mf = 0; mf < 8; ++mf)
#pragma unroll
        for (int j = 0; j < 4; ++j)
          scr[(w << 7) + mf * 16 + (lhi << 2) + j] = ssv[mf][j];
    }
    __syncthreads();
#pragma unroll
    for (int mf = 0; mf < 8; ++mf) {
#pragma unroll
      for (int j = 0; j < 4; ++j) {
        const float tot = ssv[mf][j] + scr[((w ^ 1) << 7) + mf * 16 + (lhi << 2) + j];
        const float inv = rsqrtf(tot * (1.0f / 128.0f) + EPS_RMS);
        const int m = m0 + (wr << 7) + mf * 16 + (lhi << 2) + j;
        const float* rp = rope + ((size_t)(m & 4095) << 8);
        float* orow = dout + outBase + ((size_t)m << 11) + nsec + l15;
#pragma unroll
        for (int nf = 0; nf < 4; ++nf) {
          const float tn = (acc[mf][nf][j] + biasv[nf]) * inv * nwv[nf];
          const float pn = __shfl_xor(tn, 1);     // partner col^1
          const int ch = colh + nf * 16 + l15;    // col in head
          const int jr = ch >> 1;
          const float o = fmaf(rp[jr << 2], tn, rp[(jr << 2) + 1 + (ch & 1)] * pn);
          orow[nf << 4] = o;
        }
      }
    }
  } else {
#pragma unroll
    for (int mf = 0; mf < 8; ++mf)
#pragma unroll
      for (int j = 0; j < 4; ++j) {
        const int m = m0 + (wr << 7) + mf * 16 + (lhi << 2) + j;
        float* orow = dout + outBase + ((size_t)m << 11) + nsec + l15;
#pragma unroll
        for (int nf = 0; nf < 4; ++nf) orow[nf << 4] = acc[mf][nf][j] + biasv[nf];
      }
  }
}

extern "C" void kernel_launch(void* const* d_in, const int* in_sizes, int n_in,
                              void* d_out, int out_size, void* d_ws, size_t ws_size,
                              hipStream_t stream) {
  const float* x = (const float*)d_in[0];
  const float* rope = (const float*)d_in[1];
  const float* wq = (const float*)d_in[2];
  const float* bq = (const float*)d_in[3];
  const float* wk = (const float*)d_in[4];
  const float* bk = (const float*)d_in[5];
  const float* wv = (const float*)d_in[6];
  const float* bv = (const float*)d_in[7];
  const float* qnw = (const float*)d_in[8];
  const float* knw = (const float*)d_in[9];

  unsigned short* xbf = (unsigned short*)d_ws;                 // 32 MB
  unsigned short* wbf = xbf + (size_t)M_DIM * K_DIM;           // 24 MB

  cvt_kernel<<<2048, 256, 0, stream>>>(x, xbf, M_DIM * K_DIM / 4);
  cvt_kernel<<<1024, 256, 0, stream>>>(wq, wbf, K_DIM * K_DIM / 4);
  cvt_kernel<<<1024, 256, 0, stream>>>(wk, wbf + (size_t)K_DIM * K_DIM, K_DIM * K_DIM / 4);
  cvt_kernel<<<1024, 256, 0, stream>>>(wv, wbf + (size_t)2 * K_DIM * K_DIM, K_DIM * K_DIM / 4);

  gemm_fused<<<(M_DIM / 256) * (N_DIM / 256), 512, 0, stream>>>(
      xbf, wbf, rope, bq, bk, bv, qnw, knw, (float*)d_out);
}

// Round 4
// 261.192 us; speedup vs baseline: 1.2833x; 1.0155x over previous
//
#include <hip/hip_runtime.h>

// B=2, S=4096, C=2048, HD=128, H=16
// GEMM: M=8192 (B*S), N=6144 (3*C), K=2048; out = concat(q,k,v) f32 [8192,2048] each.

#define M_DIM 8192
#define N_DIM 6144
#define K_DIM 2048
#define NKT 32            // K tiles of 64
#define EPS_RMS 1.1920929e-07f

typedef __bf16 bf16x8 __attribute__((ext_vector_type(8)));
typedef float f32x4 __attribute__((ext_vector_type(4)));

__device__ __forceinline__ void gload16(const void* g, void* l) {
  __builtin_amdgcn_global_load_lds(
      (const __attribute__((address_space(1))) unsigned int*)g,
      (__attribute__((address_space(3))) unsigned int*)l, 16, 0, 0);
}

__device__ __forceinline__ unsigned short f2bf(float f) {
  union { float f; unsigned u; } x; x.f = f;
  unsigned r = x.u + 0x7FFFu + ((x.u >> 16) & 1u);   // RNE
  return (unsigned short)(r >> 16);
}

__global__ void __launch_bounds__(256) cvt_kernel(const float* __restrict__ s,
                                                  unsigned short* __restrict__ d, int n4) {
  int i = blockIdx.x * blockDim.x + threadIdx.x;
  const int stride = gridDim.x * blockDim.x;
  for (; i < n4; i += stride) {
    const float4 v = reinterpret_cast<const float4*>(s)[i];
    ushort4 o;
    o.x = f2bf(v.x); o.y = f2bf(v.y); o.z = f2bf(v.z); o.w = f2bf(v.w);
    reinterpret_cast<ushort4*>(d)[i] = o;
  }
}

// Plain (compiler-scheduled) LDS vector load — lets hipcc emit fine-grained
// lgkmcnt interleave of ds_read_b128 with MFMA instead of a full drain.
#define LDS4(ARR, BASE, OFF) (*(const f32x4*)((const char*)(ARR) + (BASE) + (OFF)))

#define MFMA_PH(MH, NH)                                                              \
  {                                                                                  \
    _Pragma("unroll")                                                                \
    for (int mf4 = 0; mf4 < 4; ++mf4) {                                              \
      _Pragma("unroll")                                                              \
      for (int nf2 = 0; nf2 < 2; ++nf2) {                                            \
        f32x4& c = acc[(MH) * 4 + mf4][(NH) * 2 + nf2];                              \
        c = __builtin_amdgcn_mfma_f32_16x16x32_bf16(                                 \
            __builtin_bit_cast(bf16x8, Af[mf4][0]),                                  \
            __builtin_bit_cast(bf16x8, Bf[NH][nf2][0]), c, 0, 0, 0);                 \
        c = __builtin_amdgcn_mfma_f32_16x16x32_bf16(                                 \
            __builtin_bit_cast(bf16x8, Af[mf4][1]),                                  \
            __builtin_bit_cast(bf16x8, Bf[NH][nf2][1]), c, 0, 0, 0);                 \
      }                                                                              \
    }                                                                                \
  }

// 256x256 tile, BK=64, 8 waves (2M x 4N), per-wave 128x64.
// LDS: A[2 buf][4 quarters][64 rows][64 cols] bf16 = 64 KB; B same = 64 KB.
// 2 phases/K-tile, 2 barriers/K-tile:
//   ph0: plain-read A-h0(8)+B(8,both halves), stage 6-set(kt+1)={Aq0,Aq2,Bq0..3},
//        64 MFMA (quadrants (0,0),(0,1)); vmcnt(6) [drains this-kt Aq1,Aq3]; barrier.
//   ph1: plain-read A-h1(8), stage 2-set(kt+1)={Aq1,Aq3}, 64 MFMA ((1,0),(1,1));
//        vmcnt(2) [drains kt+1 6-set]; barrier.
// Outstanding VMEM <= 8 always; waits drain exactly the oldest protected set.
__global__ void __launch_bounds__(512, 2) gemm_fused(
    const unsigned short* __restrict__ xbf, const unsigned short* __restrict__ wbf,
    const float* __restrict__ rope,
    const float* __restrict__ bq, const float* __restrict__ bk, const float* __restrict__ bv,
    const float* __restrict__ qnw, const float* __restrict__ knw,
    float* __restrict__ dout) {
  const int id = blockIdx.x;
  const int sw = (id & 7) * 96 + (id >> 3);    // 768 % 8 == 0, bijective
  const int bm = sw / 24;
  const int bn = sw - bm * 24;
  const int m0 = bm << 8, n0 = bn << 8;
  const int tid = threadIdx.x;
  const int w = tid >> 6, l = tid & 63;
  const int l15 = l & 15, lhi = l >> 4;
  const int wr = w >> 2, wc = w & 3;

  __shared__ __align__(16) unsigned short As[32768];   // 64 KB
  __shared__ __align__(16) unsigned short Bs[32768];   // 64 KB

  // ---- staging (linear LDS dest, inverse-swizzled global source) ----
  const int srow = tid >> 3;                       // 0..63 within a quarter
  const int schunk = (tid & 7) ^ (srow & 7);       // involution
  const unsigned short* aSrc = xbf + ((size_t)(m0 + srow) << 11) + (schunk << 3);
  const unsigned short* bSrc = wbf + ((size_t)(n0 + srow) << 11) + (schunk << 3);
  char* aDst = (char*)As + (w << 10);
  char* bDst = (char*)Bs + (w << 10);

#define STA(KT, Q) gload16(aSrc + ((size_t)(Q) << 17) + ((KT) << 6), aDst + ((((KT) & 1) << 15) + ((Q) << 13)))
#define STB(KT, Q) gload16(bSrc + ((size_t)(Q) << 17) + ((KT) << 6), bDst + ((((KT) & 1) << 15) + ((Q) << 13)))

  // ---- read-side swizzled byte offsets (k-slot XOR row&7) ----
  const int sl0 = ((lhi ^ (l15 & 7)) << 4);        // k-slots 0..3  (k 0..31)
  const int sl1 = (((lhi + 4) ^ (l15 & 7)) << 4);  // k-slots 4..7  (k 32..63)
  unsigned a0 = (wr << 14) + (l15 << 7) + sl0;
  unsigned a1 = (wr << 14) + (l15 << 7) + sl1;
  unsigned b0 = (wc << 13) + (l15 << 7) + sl0;
  unsigned b1 = (wc << 13) + (l15 << 7) + sl1;

  f32x4 acc[8][4];
#pragma unroll
  for (int i = 0; i < 8; ++i)
#pragma unroll
    for (int j = 0; j < 4; ++j) acc[i][j] = (f32x4){0.f, 0.f, 0.f, 0.f};

  f32x4 Af[4][2];        // current A-half fragments (k-slices 0/1)
  f32x4 Bf[2][2][2];     // both B col-halves, held across the K-tile

  // ---- prologue: 6-set(kt0) then 2-set(kt0); wait 6-set, keep 2 in flight ----
  STA(0, 0); STA(0, 2);
  STB(0, 0); STB(0, 1); STB(0, 2); STB(0, 3);
  STA(0, 1); STA(0, 3);
  asm volatile("s_waitcnt vmcnt(2)" ::: "memory");
  __builtin_amdgcn_s_barrier();
  asm volatile("" ::: "memory");

  for (int kt = 0; kt < NKT; ++kt) {
    const bool notLast = (kt < NKT - 1);
    // ================ phase 0 ================
    Af[0][0] = LDS4(As, a0, 0);    Af[1][0] = LDS4(As, a0, 2048);
    Af[2][0] = LDS4(As, a0, 4096); Af[3][0] = LDS4(As, a0, 6144);
    Af[0][1] = LDS4(As, a1, 0);    Af[1][1] = LDS4(As, a1, 2048);
    Af[2][1] = LDS4(As, a1, 4096); Af[3][1] = LDS4(As, a1, 6144);
    Bf[0][0][0] = LDS4(Bs, b0, 0);    Bf[0][1][0] = LDS4(Bs, b0, 2048);
    Bf[0][0][1] = LDS4(Bs, b1, 0);    Bf[0][1][1] = LDS4(Bs, b1, 2048);
    Bf[1][0][0] = LDS4(Bs, b0, 4096); Bf[1][1][0] = LDS4(Bs, b0, 6144);
    Bf[1][0][1] = LDS4(Bs, b1, 4096); Bf[1][1][1] = LDS4(Bs, b1, 6144);
    if (notLast) {
      STA(kt + 1, 0); STA(kt + 1, 2);
      STB(kt + 1, 0); STB(kt + 1, 1); STB(kt + 1, 2); STB(kt + 1, 3);
    }
    __builtin_amdgcn_s_setprio(1);
    MFMA_PH(0, 0);
    MFMA_PH(0, 1);
    __builtin_amdgcn_s_setprio(0);
    if (notLast) { asm volatile("s_waitcnt vmcnt(6)" ::: "memory"); }
    else         { asm volatile("s_waitcnt vmcnt(0)" ::: "memory"); }
    __builtin_amdgcn_s_barrier();
    asm volatile("" ::: "memory");
    // ================ phase 1 ================
    Af[0][0] = LDS4(As, a0, 8192);  Af[1][0] = LDS4(As, a0, 10240);
    Af[2][0] = LDS4(As, a0, 12288); Af[3][0] = LDS4(As, a0, 14336);
    Af[0][1] = LDS4(As, a1, 8192);  Af[1][1] = LDS4(As, a1, 10240);
    Af[2][1] = LDS4(As, a1, 12288); Af[3][1] = LDS4(As, a1, 14336);
    if (notLast) { STA(kt + 1, 1); STA(kt + 1, 3); }
    __builtin_amdgcn_s_setprio(1);
    MFMA_PH(1, 0);
    MFMA_PH(1, 1);
    __builtin_amdgcn_s_setprio(0);
    if (notLast) { asm volatile("s_waitcnt vmcnt(2)" ::: "memory"); }
    __builtin_amdgcn_s_barrier();
    asm volatile("" ::: "memory");
    a0 ^= 32768u; a1 ^= 32768u; b0 ^= 32768u; b1 ^= 32768u;
  }

  // ---- fused epilogue: bias (+ per-head RMSNorm + RoPE for q,k) ----
  float* scr = (float*)As;                       // [8 waves][128 rows] partials
  const int sec = bn >> 3;                       // 0=q 1=k 2=v
  const int nsec = (n0 & 2047) + (wc << 6);      // col-in-section base (+nf*16+l15)
  const float* bias = sec == 0 ? bq : (sec == 1 ? bk : bv);
  float biasv[4];
#pragma unroll
  for (int nf = 0; nf < 4; ++nf) biasv[nf] = bias[nsec + nf * 16 + l15];
  const size_t outBase = ((size_t)sec << 24);

  if (sec < 2) {
    const float* nwp = sec ? knw : qnw;
    const int colh = (wc & 1) << 6;              // col-in-head base for this wave
    float nwv[4];
#pragma unroll
    for (int nf = 0; nf < 4; ++nf) nwv[nf] = nwp[colh + nf * 16 + l15];
    float ssv[8][4];
#pragma unroll
    for (int mf = 0; mf < 8; ++mf) {
#pragma unroll
      for (int j = 0; j < 4; ++j) {
        float ss = 0.f;
#pragma unroll
        for (int nf = 0; nf < 4; ++nf) {
          const float t = acc[mf][nf][j] + biasv[nf];
          ss += t * t;
        }
        ss += __shfl_xor(ss, 1);
        ss += __shfl_xor(ss, 2);
        ss += __shfl_xor(ss, 4);
        ss += __shfl_xor(ss, 8);
        ssv[mf][j] = ss;                          // sum over this wave's 64 cols
      }
    }
    if (l15 == 0) {
#pragma unroll
      for (int mf = 0; mf < 8; ++mf)
#pragma unroll
        for (int j = 0; j < 4; ++j)
          scr[(w << 7) + mf * 16 + (lhi << 2) + j] = ssv[mf][j];
    }
    __syncthreads();
#pragma unroll
    for (int mf = 0; mf < 8; ++mf) {
#pragma unroll
      for (int j = 0; j < 4; ++j) {
        const float tot = ssv[mf][j] + scr[((w ^ 1) << 7) + mf * 16 + (lhi << 2) + j];
        const float inv = rsqrtf(tot * (1.0f / 128.0f) + EPS_RMS);
        const int m = m0 + (wr << 7) + mf * 16 + (lhi << 2) + j;
        const float* rp = rope + ((size_t)(m & 4095) << 8);
        float* orow = dout + outBase + ((size_t)m << 11) + nsec + l15;
#pragma unroll
        for (int nf = 0; nf < 4; ++nf) {
          const float tn = (acc[mf][nf][j] + biasv[nf]) * inv * nwv[nf];
          const float pn = __shfl_xor(tn, 1);     // partner col^1
          const int ch = colh + nf * 16 + l15;    // col in head
          const int jr = ch >> 1;
          const float o = fmaf(rp[jr << 2], tn, rp[(jr << 2) + 1 + (ch & 1)] * pn);
          orow[nf << 4] = o;
        }
      }
    }
  } else {
#pragma unroll
    for (int mf = 0; mf < 8; ++mf)
#pragma unroll
      for (int j = 0; j < 4; ++j) {
        const int m = m0 + (wr << 7) + mf * 16 + (lhi << 2) + j;
        float* orow = dout + outBase + ((size_t)m << 11) + nsec + l15;
#pragma unroll
        for (int nf = 0; nf < 4; ++nf) orow[nf << 4] = acc[mf][nf][j] + biasv[nf];
      }
  }
}

extern "C" void kernel_launch(void* const* d_in, const int* in_sizes, int n_in,
                              void* d_out, int out_size, void* d_ws, size_t ws_size,
                              hipStream_t stream) {
  const float* x = (const float*)d_in[0];
  const float* rope = (const float*)d_in[1];
  const float* wq = (const float*)d_in[2];
  const float* bq = (const float*)d_in[3];
  const float* wk = (const float*)d_in[4];
  const float* bk = (const float*)d_in[5];
  const float* wv = (const float*)d_in[6];
  const float* bv = (const float*)d_in[7];
  const float* qnw = (const float*)d_in[8];
  const float* knw = (const float*)d_in[9];

  unsigned short* xbf = (unsigned short*)d_ws;                 // 32 MB
  unsigned short* wbf = xbf + (size_t)M_DIM * K_DIM;           // 24 MB

  cvt_kernel<<<2048, 256, 0, stream>>>(x, xbf, M_DIM * K_DIM / 4);
  cvt_kernel<<<1024, 256, 0, stream>>>(wq, wbf, K_DIM * K_DIM / 4);
  cvt_kernel<<<1024, 256, 0, stream>>>(wk, wbf + (size_t)K_DIM * K_DIM, K_DIM * K_DIM / 4);
  cvt_kernel<<<1024, 256, 0, stream>>>(wv, wbf + (size_t)2 * K_DIM * K_DIM, K_DIM * K_DIM / 4);

  gemm_fused<<<(M_DIM / 256) * (N_DIM / 256), 512, 0, stream>>>(
      xbf, wbf, rope, bq, bk, bv, qnw, knw, (float*)d_out);
}

// Round 5
// 240.313 us; speedup vs baseline: 1.3948x; 1.0869x over previous
//
#include <hip/hip_runtime.h>

// B=2, S=4096, C=2048, HD=128, H=16
// GEMM: M=8192 (B*S), N=6144 (3*C), K=2048; out = concat(q,k,v) f32 [8192,2048] each.

#define M_DIM 8192
#define N_DIM 6144
#define K_DIM 2048
#define NKT 32            // K tiles of 64
#define EPS_RMS 1.1920929e-07f

typedef __bf16 bf16x8 __attribute__((ext_vector_type(8)));
typedef float f32x4 __attribute__((ext_vector_type(4)));

__device__ __forceinline__ void gload16(const void* g, void* l) {
  __builtin_amdgcn_global_load_lds(
      (const __attribute__((address_space(1))) unsigned int*)g,
      (__attribute__((address_space(3))) unsigned int*)l, 16, 0, 0);
}

__device__ __forceinline__ unsigned short f2bf(float f) {
  union { float f; unsigned u; } x; x.f = f;
  unsigned r = x.u + 0x7FFFu + ((x.u >> 16) & 1u);   // RNE
  return (unsigned short)(r >> 16);
}

__global__ void __launch_bounds__(256) cvt_kernel(const float* __restrict__ s,
                                                  unsigned short* __restrict__ d, int n4) {
  int i = blockIdx.x * blockDim.x + threadIdx.x;
  const int stride = gridDim.x * blockDim.x;
  for (; i < n4; i += stride) {
    const float4 v = reinterpret_cast<const float4*>(s)[i];
    ushort4 o;
    o.x = f2bf(v.x); o.y = f2bf(v.y); o.z = f2bf(v.z); o.w = f2bf(v.w);
    reinterpret_cast<ushort4*>(d)[i] = o;
  }
}

#define LDS4(ARR, BASE, OFF) (*(const f32x4*)((const char*)(ARR) + (BASE) + (OFF)))

// sched_group_barrier masks: MFMA=0x8, DS_READ=0x100
#define SGB_DS(N)   __builtin_amdgcn_sched_group_barrier(0x100, (N), 0)
#define SGB_MFMA(N) __builtin_amdgcn_sched_group_barrier(0x8, (N), 0)

#define MFMA_PH(MH, NH)                                                              \
  {                                                                                  \
    _Pragma("unroll")                                                                \
    for (int mf4 = 0; mf4 < 4; ++mf4) {                                              \
      _Pragma("unroll")                                                              \
      for (int nf2 = 0; nf2 < 2; ++nf2) {                                            \
        f32x4& c = acc[(MH) * 4 + mf4][(NH) * 2 + nf2];                              \
        c = __builtin_amdgcn_mfma_f32_16x16x32_bf16(                                 \
            __builtin_bit_cast(bf16x8, Af[mf4][0]),                                  \
            __builtin_bit_cast(bf16x8, Bf[NH][nf2][0]), c, 0, 0, 0);                 \
        c = __builtin_amdgcn_mfma_f32_16x16x32_bf16(                                 \
            __builtin_bit_cast(bf16x8, Af[mf4][1]),                                  \
            __builtin_bit_cast(bf16x8, Bf[NH][nf2][1]), c, 0, 0, 0);                 \
      }                                                                              \
    }                                                                                \
  }

// 256x256 tile, BK=64, 8 waves (2M x 4N), per-wave 128x64.
// LDS: A[2 buf][4 quarters][64 rows][64 cols] bf16 = 64 KB; B same = 64 KB.
// 2 phases/K-tile, 2 barriers/K-tile; reads ordered for earliest MFMA readiness;
// sched_group_barrier forces DS_READ/MFMA interleave within each phase.
__global__ void __launch_bounds__(512, 2) gemm_fused(
    const unsigned short* __restrict__ xbf, const unsigned short* __restrict__ wbf,
    const float* __restrict__ rope,
    const float* __restrict__ bq, const float* __restrict__ bk, const float* __restrict__ bv,
    const float* __restrict__ qnw, const float* __restrict__ knw,
    float* __restrict__ dout) {
  const int id = blockIdx.x;
  // XCD-aware, bm-inner: XCD x owns bm in [4x,4x+4), bm varies fastest ->
  // concurrent L2 working set ~12 MB (8 B-panels + 4 A-panels) instead of ~26.
  const int xcd = id & 7;
  const int j = id >> 3;                 // 0..95
  const int bm = (xcd << 2) | (j & 3);   // 0..31
  const int bn = j >> 2;                 // 0..23
  const int m0 = bm << 8, n0 = bn << 8;
  const int tid = threadIdx.x;
  const int w = tid >> 6, l = tid & 63;
  const int l15 = l & 15, lhi = l >> 4;
  const int wr = w >> 2, wc = w & 3;

  __shared__ __align__(16) unsigned short As[32768];   // 64 KB
  __shared__ __align__(16) unsigned short Bs[32768];   // 64 KB

  // ---- staging (linear LDS dest, inverse-swizzled global source) ----
  const int srow = tid >> 3;                       // 0..63 within a quarter
  const int schunk = (tid & 7) ^ (srow & 7);       // involution
  const unsigned short* aSrc = xbf + ((size_t)(m0 + srow) << 11) + (schunk << 3);
  const unsigned short* bSrc = wbf + ((size_t)(n0 + srow) << 11) + (schunk << 3);
  char* aDst = (char*)As + (w << 10);
  char* bDst = (char*)Bs + (w << 10);

#define STA(KT, Q) gload16(aSrc + ((size_t)(Q) << 17) + ((KT) << 6), aDst + ((((KT) & 1) << 15) + ((Q) << 13)))
#define STB(KT, Q) gload16(bSrc + ((size_t)(Q) << 17) + ((KT) << 6), bDst + ((((KT) & 1) << 15) + ((Q) << 13)))

  // ---- read-side swizzled byte offsets (k-slot XOR row&7) ----
  const int sl0 = ((lhi ^ (l15 & 7)) << 4);        // k-slots 0..3  (k 0..31)
  const int sl1 = (((lhi + 4) ^ (l15 & 7)) << 4);  // k-slots 4..7  (k 32..63)
  unsigned a0 = (wr << 14) + (l15 << 7) + sl0;
  unsigned a1 = (wr << 14) + (l15 << 7) + sl1;
  unsigned b0 = (wc << 13) + (l15 << 7) + sl0;
  unsigned b1 = (wc << 13) + (l15 << 7) + sl1;

  f32x4 acc[8][4];
#pragma unroll
  for (int i = 0; i < 8; ++i)
#pragma unroll
    for (int jj = 0; jj < 4; ++jj) acc[i][jj] = (f32x4){0.f, 0.f, 0.f, 0.f};

  f32x4 Af[4][2];        // current A-half fragments (k-slices 0/1)
  f32x4 Bf[2][2][2];     // both B col-halves, held across the K-tile

  // ---- prologue: 6-set(kt0) then 2-set(kt0); wait 6-set, keep 2 in flight ----
  STA(0, 0); STA(0, 2);
  STB(0, 0); STB(0, 1); STB(0, 2); STB(0, 3);
  STA(0, 1); STA(0, 3);
  asm volatile("s_waitcnt vmcnt(2)" ::: "memory");
  __builtin_amdgcn_s_barrier();
  asm volatile("" ::: "memory");

  for (int kt = 0; kt < NKT; ++kt) {
    const bool notLast = (kt < NKT - 1);
    // ================ phase 0 : A-h0 + B(all), MFMA Q00,Q01 ================
    // reads ordered so chain (mf0,nf0) is ready after 4 reads
    Af[0][0] = LDS4(As, a0, 0);        Af[0][1] = LDS4(As, a1, 0);
    Bf[0][0][0] = LDS4(Bs, b0, 0);     Bf[0][0][1] = LDS4(Bs, b1, 0);
    Bf[0][1][0] = LDS4(Bs, b0, 2048);  Bf[0][1][1] = LDS4(Bs, b1, 2048);
    Af[1][0] = LDS4(As, a0, 2048);     Af[1][1] = LDS4(As, a1, 2048);
    Af[2][0] = LDS4(As, a0, 4096);     Af[2][1] = LDS4(As, a1, 4096);
    Af[3][0] = LDS4(As, a0, 6144);     Af[3][1] = LDS4(As, a1, 6144);
    Bf[1][0][0] = LDS4(Bs, b0, 4096);  Bf[1][0][1] = LDS4(Bs, b1, 4096);
    Bf[1][1][0] = LDS4(Bs, b0, 6144);  Bf[1][1][1] = LDS4(Bs, b1, 6144);
    if (notLast) {
      STA(kt + 1, 0); STA(kt + 1, 2);
      STB(kt + 1, 0); STB(kt + 1, 1); STB(kt + 1, 2); STB(kt + 1, 3);
    }
    __builtin_amdgcn_s_setprio(1);
    MFMA_PH(0, 0);
    MFMA_PH(0, 1);
    // forced interleave: {DS4,M2,DS2,M2,DS2,M4,DS2,M4,DS2,M4,DS4,M16}
    SGB_DS(4);  SGB_MFMA(2);
    SGB_DS(2);  SGB_MFMA(2);
    SGB_DS(2);  SGB_MFMA(4);
    SGB_DS(2);  SGB_MFMA(4);
    SGB_DS(2);  SGB_MFMA(4);
    SGB_DS(4);  SGB_MFMA(16);
    __builtin_amdgcn_s_setprio(0);
    if (notLast) { asm volatile("s_waitcnt vmcnt(6)" ::: "memory"); }
    else         { asm volatile("s_waitcnt vmcnt(0)" ::: "memory"); }
    __builtin_amdgcn_s_barrier();
    asm volatile("" ::: "memory");
    // ================ phase 1 : A-h1, MFMA Q10,Q11 (B in regs) ================
    Af[0][0] = LDS4(As, a0, 8192);  Af[0][1] = LDS4(As, a1, 8192);
    Af[1][0] = LDS4(As, a0, 10240); Af[1][1] = LDS4(As, a1, 10240);
    Af[2][0] = LDS4(As, a0, 12288); Af[2][1] = LDS4(As, a1, 12288);
    Af[3][0] = LDS4(As, a0, 14336); Af[3][1] = LDS4(As, a1, 14336);
    if (notLast) { STA(kt + 1, 1); STA(kt + 1, 3); }
    __builtin_amdgcn_s_setprio(1);
    MFMA_PH(1, 0);
    MFMA_PH(1, 1);
    // forced interleave: {DS2,M4}x4, M16
    SGB_DS(2);  SGB_MFMA(4);
    SGB_DS(2);  SGB_MFMA(4);
    SGB_DS(2);  SGB_MFMA(4);
    SGB_DS(2);  SGB_MFMA(4);
    SGB_MFMA(16);
    __builtin_amdgcn_s_setprio(0);
    if (notLast) { asm volatile("s_waitcnt vmcnt(2)" ::: "memory"); }
    __builtin_amdgcn_s_barrier();
    asm volatile("" ::: "memory");
    a0 ^= 32768u; a1 ^= 32768u; b0 ^= 32768u; b1 ^= 32768u;
  }

  // ---- fused epilogue: bias (+ per-head RMSNorm + RoPE for q,k) ----
  float* scr = (float*)As;                       // [8 waves][128 rows] partials
  const int sec = bn >> 3;                       // 0=q 1=k 2=v
  const int nsec = (n0 & 2047) + (wc << 6);      // col-in-section base (+nf*16+l15)
  const float* bias = sec == 0 ? bq : (sec == 1 ? bk : bv);
  float biasv[4];
#pragma unroll
  for (int nf = 0; nf < 4; ++nf) biasv[nf] = bias[nsec + nf * 16 + l15];
  const size_t outBase = ((size_t)sec << 24);

  if (sec < 2) {
    const float* nwp = sec ? knw : qnw;
    const int colh = (wc & 1) << 6;              // col-in-head base for this wave
    float nwv[4];
#pragma unroll
    for (int nf = 0; nf < 4; ++nf) nwv[nf] = nwp[colh + nf * 16 + l15];
    float ssv[8][4];
#pragma unroll
    for (int mf = 0; mf < 8; ++mf) {
#pragma unroll
      for (int jj = 0; jj < 4; ++jj) {
        float ss = 0.f;
#pragma unroll
        for (int nf = 0; nf < 4; ++nf) {
          const float t = acc[mf][nf][jj] + biasv[nf];
          ss += t * t;
        }
        ss += __shfl_xor(ss, 1);
        ss += __shfl_xor(ss, 2);
        ss += __shfl_xor(ss, 4);
        ss += __shfl_xor(ss, 8);
        ssv[mf][jj] = ss;                        // sum over this wave's 64 cols
      }
    }
    if (l15 == 0) {
#pragma unroll
      for (int mf = 0; mf < 8; ++mf)
#pragma unroll
        for (int jj = 0; jj < 4; ++jj)
          scr[(w << 7) + mf * 16 + (lhi << 2) + jj] = ssv[mf][jj];
    }
    __syncthreads();
#pragma unroll
    for (int mf = 0; mf < 8; ++mf) {
#pragma unroll
      for (int jj = 0; jj < 4; ++jj) {
        const float tot = ssv[mf][jj] + scr[((w ^ 1) << 7) + mf * 16 + (lhi << 2) + jj];
        const float inv = rsqrtf(tot * (1.0f / 128.0f) + EPS_RMS);
        const int m = m0 + (wr << 7) + mf * 16 + (lhi << 2) + jj;
        const float* rp = rope + ((size_t)(m & 4095) << 8);
        float* orow = dout + outBase + ((size_t)m << 11) + nsec + l15;
#pragma unroll
        for (int nf = 0; nf < 4; ++nf) {
          const float tn = (acc[mf][nf][jj] + biasv[nf]) * inv * nwv[nf];
          const float pn = __shfl_xor(tn, 1);     // partner col^1
          const int ch = colh + nf * 16 + l15;    // col in head
          const int jr = ch >> 1;
          const float o = fmaf(rp[jr << 2], tn, rp[(jr << 2) + 1 + (ch & 1)] * pn);
          orow[nf << 4] = o;
        }
      }
    }
  } else {
#pragma unroll
    for (int mf = 0; mf < 8; ++mf)
#pragma unroll
      for (int jj = 0; jj < 4; ++jj) {
        const int m = m0 + (wr << 7) + mf * 16 + (lhi << 2) + jj;
        float* orow = dout + outBase + ((size_t)m << 11) + nsec + l15;
#pragma unroll
        for (int nf = 0; nf < 4; ++nf) orow[nf << 4] = acc[mf][nf][jj] + biasv[nf];
      }
  }
}

extern "C" void kernel_launch(void* const* d_in, const int* in_sizes, int n_in,
                              void* d_out, int out_size, void* d_ws, size_t ws_size,
                              hipStream_t stream) {
  const float* x = (const float*)d_in[0];
  const float* rope = (const float*)d_in[1];
  const float* wq = (const float*)d_in[2];
  const float* bq = (const float*)d_in[3];
  const float* wk = (const float*)d_in[4];
  const float* bk = (const float*)d_in[5];
  const float* wv = (const float*)d_in[6];
  const float* bv = (const float*)d_in[7];
  const float* qnw = (const float*)d_in[8];
  const float* knw = (const float*)d_in[9];

  unsigned short* xbf = (unsigned short*)d_ws;                 // 32 MB
  unsigned short* wbf = xbf + (size_t)M_DIM * K_DIM;           // 24 MB

  cvt_kernel<<<2048, 256, 0, stream>>>(x, xbf, M_DIM * K_DIM / 4);
  cvt_kernel<<<1024, 256, 0, stream>>>(wq, wbf, K_DIM * K_DIM / 4);
  cvt_kernel<<<1024, 256, 0, stream>>>(wk, wbf + (size_t)K_DIM * K_DIM, K_DIM * K_DIM / 4);
  cvt_kernel<<<1024, 256, 0, stream>>>(wv, wbf + (size_t)2 * K_DIM * K_DIM, K_DIM * K_DIM / 4);

  gemm_fused<<<(M_DIM / 256) * (N_DIM / 256), 512, 0, stream>>>(
      xbf, wbf, rope, bq, bk, bv, qnw, knw, (float*)d_out);
}